// Round 6
// baseline (268.883 us; speedup 1.0000x reference)
//
#include <hip/hip_runtime.h>
#include <hip/hip_fp16.h>

// ROIAlign forward (PH=PW=7, SCALE=0.25, SR=2, ALIGNED=true)
//   input [4,256,200,200] fp32 NCHW, rois [512,5], out [512,256,7,7] fp32
//
// Round-6: whole-plane LDS blocks (zero staging redundancy) + packed meta.
//   - R3/R5 strip structure plateaued at kernel-sum ~93-97us; throughput
//     model says ~30us -> the structure (16 block-generations/CU, each
//     staging-front-loaded with ~3 compute iters, 68B/output meta chain)
//     is the residual.
//   - Block=(c,b), 1024 thr, stages the FULL 200x200 plane: 160000 B LDS
//     (gfx950 LDS = 163840 B). Total staged = input exactly (164 MB, was
//     183). 4 generations/CU; generation == batch -> perfectly balanced.
//   - No strip lists; per-batch roi list only. Meta packed to 16 B/axis:
//     uchar4 indices + 4 x fp16 weights (err <= max|F| * 2^-11 ~ 0.002,
//     threshold 0.0425, base absmax 0.0078).
// Fixed harness overhead ~167us (640MB ws poison + input restore + out
// poison) untouchable; target kernel-sum -> ~35us.

#define R_PH 7
#define R_PW 7
#define R_SR 2
#define R_SCALE 0.25f
#define R_C 256
#define R_H 200
#define R_W 200
#define R_HW (R_H * R_W)
#define R_B 4

__device__ __forceinline__ void axis_sample(float start, float bin, int p, int s, int size,
                                            int& lo, int& hi, float& wlo, float& whi) {
    // coord = start + p*bin + (s+0.5)*bin/SR   (same grouping as reference)
    float coord = (start + (float)p * bin) + ((float)s + 0.5f) * bin * (1.0f / R_SR);
    bool valid = (coord >= -1.0f) && (coord <= (float)size);
    float c = fmaxf(coord, 0.0f);
    int lo_raw = (int)floorf(c);
    bool at_edge = lo_raw >= size - 1;
    lo = at_edge ? size - 1 : lo_raw;
    hi = at_edge ? size - 1 : lo_raw + 1;
    float cv = at_edge ? (float)(size - 1) : c;
    float frac = cv - (float)lo;          // weight toward hi
    whi = valid ? frac : 0.0f;
    wlo = valid ? (1.0f - frac) : 0.0f;
}

__device__ __forceinline__ unsigned pack_h2(float a, float b) {
    __half2 h = __floats2half2_rn(a, b);
    return *(unsigned*)&h;
}

// ---------- Pre-kernel: per-batch roi lists + packed sample metadata ----------
// ws ints: bcnt[4] | blist[4][N] | ymeta uint4[N*7] | xmeta uint4[N*7]
__global__ void __launch_bounds__(512)
build_meta(const float* __restrict__ rois, int N, int* __restrict__ ws) {
    __shared__ int lc[R_B];
    int t = threadIdx.x;
    if (t < R_B) lc[t] = 0;
    __syncthreads();
    int*   blist = ws + R_B;
    uint4* ymeta = (uint4*)(blist + R_B * N);
    uint4* xmeta = ymeta + N * R_PH;

    for (int n = t; n < N; n += 512) {
        const float* r = rois + (size_t)n * 5;
        int b = (int)r[0];
        int pos = atomicAdd(&lc[b], 1);
        blist[b * N + pos] = n;
        float sx = r[1] * R_SCALE - 0.5f;
        float sy = r[2] * R_SCALE - 0.5f;
        float ex = r[3] * R_SCALE - 0.5f;
        float ey = r[4] * R_SCALE - 0.5f;
        float binw = (ex - sx) * (1.0f / R_PW);
        float binh = (ey - sy) * (1.0f / R_PH);
        for (int p = 0; p < R_PH; ++p) {   // PH == PW: one loop for both axes
            int lo0, hi0, lo1, hi1; float wl0, wh0, wl1, wh1;
            // y axis: fold 0.25 mean factor into weights
            axis_sample(sy, binh, p, 0, R_H, lo0, hi0, wl0, wh0);
            axis_sample(sy, binh, p, 1, R_H, lo1, hi1, wl1, wh1);
            uint4 m;
            m.x = (unsigned)lo0 | ((unsigned)hi0 << 8) | ((unsigned)lo1 << 16) | ((unsigned)hi1 << 24);
            m.y = pack_h2(wl0 * 0.25f, wh0 * 0.25f);
            m.z = pack_h2(wl1 * 0.25f, wh1 * 0.25f);
            m.w = 0;
            ymeta[n * R_PH + p] = m;
            // x axis
            axis_sample(sx, binw, p, 0, R_W, lo0, hi0, wl0, wh0);
            axis_sample(sx, binw, p, 1, R_W, lo1, hi1, wl1, wh1);
            m.x = (unsigned)lo0 | ((unsigned)hi0 << 8) | ((unsigned)lo1 << 16) | ((unsigned)hi1 << 24);
            m.y = pack_h2(wl0, wh0);
            m.z = pack_h2(wl1, wh1);
            m.w = 0;
            xmeta[n * R_PH + p] = m;
        }
    }
    __syncthreads();
    if (t < R_B) ws[t] = lc[t];
}

// ---------- Main: whole-plane LDS gather ----------
// grid (C=256, B=4), block 1024. LDS = full plane 160000 B -> 1 block/CU.
__global__ void __launch_bounds__(1024, 4)
roi_plane(const float* __restrict__ input,
          const int* __restrict__ ws, int N,
          float* __restrict__ out) {
    __shared__ float pl[R_HW];          // 160000 B (gfx950 LDS 163840)
    int c = blockIdx.x;
    int b = blockIdx.y;
    int t = threadIdx.x;

    // stage entire (b,c) plane, coalesced float4
    const float4* src = (const float4*)(input + (size_t)(b * R_C + c) * R_HW);
    float4* dst = (float4*)pl;
    for (int i = t; i < R_HW / 4; i += 1024) dst[i] = src[i];

    int cnt = ws[b];                    // rois in this batch
    const int*   blist = ws + R_B + b * N;
    const uint4* ymeta = (const uint4*)(ws + R_B + R_B * N);
    const uint4* xmeta = ymeta + N * R_PH;
    __syncthreads();

    int items = cnt * 49;
    for (int i = t; i < items; i += 1024) {
        int e  = i / 49;
        int rr = i - e * 49;
        int ph = rr / 7;
        int pw = rr - ph * 7;
        int n  = blist[e];
        uint4 ym = ymeta[n * R_PH + ph];
        uint4 xm = xmeta[n * R_PH + pw];

        const float* p0 = pl + (ym.x & 255u) * R_W;
        const float* p1 = pl + ((ym.x >> 8) & 255u) * R_W;
        const float* p2 = pl + ((ym.x >> 16) & 255u) * R_W;
        const float* p3 = pl + (ym.x >> 24) * R_W;
        int c0 = xm.x & 255u, c1 = (xm.x >> 8) & 255u, c2 = (xm.x >> 16) & 255u, c3 = xm.x >> 24;

        float2 wy01 = __half22float2(*(const __half2*)&ym.y);
        float2 wy23 = __half22float2(*(const __half2*)&ym.z);
        float2 wx01 = __half22float2(*(const __half2*)&xm.y);
        float2 wx23 = __half22float2(*(const __half2*)&xm.z);

        float s0 = wx01.x * p0[c0] + wx01.y * p0[c1] + wx23.x * p0[c2] + wx23.y * p0[c3];
        float s1 = wx01.x * p1[c0] + wx01.y * p1[c1] + wx23.x * p1[c2] + wx23.y * p1[c3];
        float s2 = wx01.x * p2[c0] + wx01.y * p2[c1] + wx23.x * p2[c2] + wx23.y * p2[c3];
        float s3 = wx01.x * p3[c0] + wx01.y * p3[c1] + wx23.x * p3[c2] + wx23.y * p3[c3];
        // 0.25 mean factor folded into wy
        out[(size_t)(n * R_C + c) * 49 + rr] =
            wy01.x * s0 + wy01.y * s1 + wy23.x * s2 + wy23.y * s3;
    }
}

// ---------- Fallback: round-1 single-pass kernel (if ws too small) ----------
__global__ void __launch_bounds__(256)
roi_align_fwd(const float* __restrict__ input,
              const float* __restrict__ rois,
              float* __restrict__ out, int total) {
    int idx = blockIdx.x * blockDim.x + threadIdx.x;
    if (idx >= total) return;
    int pw = idx % R_PW;
    int ph = (idx / R_PW) % R_PH;
    int c  = (idx / (R_PW * R_PH)) % R_C;
    int n  = idx / (R_PW * R_PH * R_C);
    const float* r = rois + (size_t)n * 5;
    int   b  = (int)r[0];
    float sx = r[1] * R_SCALE - 0.5f;
    float sy = r[2] * R_SCALE - 0.5f;
    float ex = r[3] * R_SCALE - 0.5f;
    float ey = r[4] * R_SCALE - 0.5f;
    float bin_w = (ex - sx) * (1.0f / R_PW);
    float bin_h = (ey - sy) * (1.0f / R_PH);
    const float* plane = input + (size_t)(b * R_C + c) * R_HW;
    int   ylo[R_SR], yhi[R_SR], xlo[R_SR], xhi[R_SR];
    float wylo[R_SR], wyhi[R_SR], wxlo[R_SR], wxhi[R_SR];
#pragma unroll
    for (int s = 0; s < R_SR; ++s) {
        axis_sample(sy, bin_h, ph, s, R_H, ylo[s], yhi[s], wylo[s], wyhi[s]);
        axis_sample(sx, bin_w, pw, s, R_W, xlo[s], xhi[s], wxlo[s], wxhi[s]);
    }
    float acc = 0.0f;
#pragma unroll
    for (int ys = 0; ys < R_SR; ++ys) {
        const float* row_lo = plane + ylo[ys] * R_W;
        const float* row_hi = plane + yhi[ys] * R_W;
#pragma unroll
        for (int xs = 0; xs < R_SR; ++xs) {
            acc += wylo[ys] * (wxlo[xs] * row_lo[xlo[xs]] + wxhi[xs] * row_lo[xhi[xs]])
                 + wyhi[ys] * (wxlo[xs] * row_hi[xlo[xs]] + wxhi[xs] * row_hi[xhi[xs]]);
        }
    }
    out[idx] = acc * (1.0f / (R_SR * R_SR));
}

extern "C" void kernel_launch(void* const* d_in, const int* in_sizes, int n_in,
                              void* d_out, int out_size, void* d_ws, size_t ws_size,
                              hipStream_t stream) {
    const float* input = (const float*)d_in[0];
    const float* rois  = (const float*)d_in[1];
    float* out = (float*)d_out;
    int N = in_sizes[1] / 5;

    // bytes: bcnt[4] + blist[4*N] + ymeta/xmeta uint4[N*7] each
    size_t ws_needed = (size_t)(R_B + R_B * N) * sizeof(int)
                     + (size_t)2 * N * R_PH * sizeof(uint4);   // ~123 KB @ N=512
    if (ws_size >= ws_needed) {
        int* ws = (int*)d_ws;
        build_meta<<<1, 512, 0, stream>>>(rois, N, ws);
        dim3 grid(R_C, R_B);                // c fastest -> generation == batch
        roi_plane<<<grid, 1024, 0, stream>>>(input, ws, N, out);
    } else {
        int total = out_size;
        roi_align_fwd<<<(total + 255) / 256, 256, 0, stream>>>(input, rois, out, total);
    }
}